// Round 8
// baseline (233.210 us; speedup 1.0000x reference)
//
#include <hip/hip_runtime.h>
#include <hip/hip_bf16.h>
#include <math.h>

// Problem constants
#define B_    2
#define NH_   8
#define NL_   4
#define NP_   4
#define HD_   32
#define S_    13294
#define L_    13294
#define M_    26588

__device__ __constant__ int c_H[NL_]     = {100, 50, 25, 13};
__device__ __constant__ int c_W[NL_]     = {100, 50, 25, 13};
__device__ __constant__ int c_start[NL_] = {0, 10000, 12500, 13125};

typedef __attribute__((ext_vector_type(8))) _Float16 f16x8;
typedef __attribute__((ext_vector_type(4))) _Float16 f16x4;
typedef __attribute__((ext_vector_type(2))) _Float16 f16x2;
typedef __attribute__((ext_vector_type(4))) float    float4v;

__device__ __forceinline__ unsigned short f2h(float f) {
    _Float16 h = (_Float16)f;
    return __builtin_bit_cast(unsigned short, h);
}
__device__ __forceinline__ float h2f(unsigned short u) {
    _Float16 h = __builtin_bit_cast(_Float16, u);
    return (float)h;
}
__device__ __forceinline__ f16x2 pkrtz(float a, float b) {
    return __builtin_bit_cast(f16x2, __builtin_amdgcn_cvt_pkrtz(a, b));
}

// ---------------------------------------------------------------------------
// Weight prep: transpose W's to [N][K] fp16, fused off|attn weights + bias.
// ---------------------------------------------------------------------------
__global__ __launch_bounds__(256) void prep_weights(
    const float* __restrict__ W_val, const float* __restrict__ W_off,
    const float* __restrict__ W_attn, const float* __restrict__ b_off,
    const float* __restrict__ b_attn, const float* __restrict__ W_out,
    unsigned short* __restrict__ wt_val, unsigned short* __restrict__ wt_oa,
    unsigned short* __restrict__ wt_out, float* __restrict__ bias_oa)
{
    int i = blockIdx.x * 256 + threadIdx.x;
    if (i < 65536) {
        int n = i >> 8, k = i & 255;
        wt_val[i] = f2h(W_val[k * 256 + n]);
    } else if (i < 65536 + 98304) {
        int j = i - 65536;
        int n = j >> 8, k = j & 255;   // n in [0,384)
        float v = (n < 256) ? W_off[k * 256 + n] : W_attn[k * 128 + (n - 256)];
        wt_oa[j] = f2h(v);
    } else if (i < 65536 + 98304 + 65536) {
        int j = i - 163840;
        int n = j >> 8, k = j & 255;
        wt_out[j] = f2h(W_out[k * 256 + n]);
    } else if (i < 229376 + 384) {
        int j = i - 229376;
        bias_oa[j] = (j < 256) ? b_off[j] : b_attn[j - 256];
    }
}

// ---------------------------------------------------------------------------
// Value projection: val_f16[M,256] = value @ wt_val^T + b_val.
//   32-row x 256-col tiles, 831 blocks, 4 waves (each 32x64).
//   A: depth-4 register prefetch ring (~3 K-iters of vmcnt slack) ->
//      double-buffered LDS, one barrier/iter. B: direct-from-global, depth-2.
// ---------------------------------------------------------------------------
__global__ __launch_bounds__(256, 4) void val_proj(
    const float* __restrict__ value,
    const unsigned short* __restrict__ wt_val,
    const float* __restrict__ b_val,
    unsigned short* __restrict__ val_f16)
{
    __shared__ unsigned short As[2][32][40];

    const int tid  = threadIdx.x;
    const int lane = tid & 63;
    const int wave = tid >> 6;
    const int rowBase = blockIdx.x * 32;
    const int wcol = wave * 64;

    const int r  = tid >> 3;           // 0..31 A row
    const int ko = (tid & 7) * 4;      // float offset in BK=32
    int arow = rowBase + r; if (arow >= M_) arow = M_ - 1;   // clamp (writes guarded)
    const float* aptr = value + (size_t)arow * 256 + ko;

    const int fr = lane & 15;
    const int fk = (lane >> 4) * 8;

    const unsigned short* bb[4];
#pragma unroll
    for (int t = 0; t < 4; ++t)
        bb[t] = wt_val + (size_t)(wcol + t * 16 + fr) * 256 + fk;

    float4 ra[4];
    f16x8 curB[4], nxtB[4];
    float4v acc[2][4] = {};

    auto stA = [&](int slot, int buf) {
        f16x2 p0 = pkrtz(ra[slot].x, ra[slot].y);
        f16x2 p1 = pkrtz(ra[slot].z, ra[slot].w);
        f16x4 v; v[0] = p0[0]; v[1] = p0[1]; v[2] = p1[0]; v[3] = p1[1];
        *reinterpret_cast<f16x4*>(&As[buf][r][ko]) = v;
    };

    // prologue: 4 A-chunks + first B in flight
#pragma unroll
    for (int c = 0; c < 4; ++c)
        ra[c] = *reinterpret_cast<const float4*>(aptr + c * 32);
#pragma unroll
    for (int t = 0; t < 4; ++t)
        curB[t] = *reinterpret_cast<const f16x8*>(bb[t]);
    stA(0, 0);

#pragma unroll
    for (int it = 0; it < 8; ++it) {
        __syncthreads();
        f16x8 af0 = *reinterpret_cast<const f16x8*>(&As[it & 1][fr][fk]);
        f16x8 af1 = *reinterpret_cast<const f16x8*>(&As[it & 1][16 + fr][fk]);
        if (it < 7) {
            stA((it + 1) & 3, (it + 1) & 1);
            if (it < 4)
                ra[(it + 4) & 3] = *reinterpret_cast<const float4*>(aptr + (it + 4) * 32);
#pragma unroll
            for (int t = 0; t < 4; ++t)
                nxtB[t] = *reinterpret_cast<const f16x8*>(bb[t] + (it + 1) * 32);
        }
#pragma unroll
        for (int nt = 0; nt < 4; ++nt) {
            acc[0][nt] = __builtin_amdgcn_mfma_f32_16x16x32_f16(af0, curB[nt], acc[0][nt], 0, 0, 0);
            acc[1][nt] = __builtin_amdgcn_mfma_f32_16x16x32_f16(af1, curB[nt], acc[1][nt], 0, 0, 0);
        }
        if (it < 7) {
#pragma unroll
            for (int t = 0; t < 4; ++t) curB[t] = nxtB[t];
        }
    }

    const int dn  = lane & 15;
    const int dm0 = (lane >> 4) * 4;
#pragma unroll
    for (int mt = 0; mt < 2; ++mt)
#pragma unroll
        for (int nt = 0; nt < 4; ++nt) {
            const int col = wcol + nt * 16 + dn;
            const float bv = b_val[col];
#pragma unroll
            for (int rr = 0; rr < 4; ++rr) {
                const int row = rowBase + mt * 16 + dm0 + rr;
                if (row < M_)
                    val_f16[(size_t)row * 256 + col] = f2h(acc[mt][nt][rr] + bv);
            }
        }
}

// ---------------------------------------------------------------------------
// Mega-kernel: per block of 16 queries:
//   A) stage query tile -> LDS, oa = q @ wt_oa^T + bias (MFMA, M=16 tile)
//   B/C) x2: softmax+corner pack (8 q) -> gather (8 q) -> acc in LDS
//   D) out = acc @ wt_out^T + b_out (MFMA), write final output
// LDS ~37.3 KB -> 4 blocks/CU.
// ---------------------------------------------------------------------------
__global__ __launch_bounds__(256, 4) void mega(
    const unsigned short* __restrict__ val,    // [B,S,256] fp16
    const float* __restrict__ query,           // [M,256]
    const float* __restrict__ refp,            // [M,4,2]
    const unsigned short* __restrict__ wt_oa,  // [384][256] fp16
    const unsigned short* __restrict__ wt_out, // [256][256] fp16
    const float* __restrict__ bias_oa,         // [384]
    const float* __restrict__ b_out,           // [256]
    float* __restrict__ out)                   // [M,256]
{
    const int tid  = threadIdx.x;
    const int lane = tid & 63;
    const int wave = tid >> 6;
    const int q0   = blockIdx.x * 16;

    __shared__ unsigned short sQA[16][264];   // 8.25 KB: query tile, later acc
    __shared__ unsigned short sOA[16][384];   // 12 KB: oa result fp16
    __shared__ float sMS[16][8][2];           // 1 KB
    __shared__ int   sPack[8][4][16][8];      // 16 KB (half-group)

    const int fr = lane & 15;
    const int fk = (lane >> 4) * 8;
    const int dn  = lane & 15;
    const int dm0 = (lane >> 4) * 4;

    // ---- stage query tile (16 rows fp32 -> fp16 LDS) ----
    {
        const int r = tid >> 4;              // 0..15
        const int c = (tid & 15) * 16;       // float col base
        const int bq = min(q0 + r, M_ - 1);
        const float* qp = query + (size_t)bq * 256 + c;
        float4 f0 = *reinterpret_cast<const float4*>(qp);
        float4 f1 = *reinterpret_cast<const float4*>(qp + 4);
        float4 f2 = *reinterpret_cast<const float4*>(qp + 8);
        float4 f3 = *reinterpret_cast<const float4*>(qp + 12);
        f16x8 h0, h1;
        f16x2 p;
        p = pkrtz(f0.x, f0.y); h0[0] = p[0]; h0[1] = p[1];
        p = pkrtz(f0.z, f0.w); h0[2] = p[0]; h0[3] = p[1];
        p = pkrtz(f1.x, f1.y); h0[4] = p[0]; h0[5] = p[1];
        p = pkrtz(f1.z, f1.w); h0[6] = p[0]; h0[7] = p[1];
        p = pkrtz(f2.x, f2.y); h1[0] = p[0]; h1[1] = p[1];
        p = pkrtz(f2.z, f2.w); h1[2] = p[0]; h1[3] = p[1];
        p = pkrtz(f3.x, f3.y); h1[4] = p[0]; h1[5] = p[1];
        p = pkrtz(f3.z, f3.w); h1[6] = p[0]; h1[7] = p[1];
        *reinterpret_cast<f16x8*>(&sQA[r][c]) = h0;
        *reinterpret_cast<f16x8*>(&sQA[r][c + 8]) = h1;
    }
    __syncthreads();

    // ---- phase A: oa projection (wave w -> cols w*96..+96, 6 n-tiles) ----
    {
        const int wcol = wave * 96;
        const unsigned short* bb[6];
#pragma unroll
        for (int t = 0; t < 6; ++t)
            bb[t] = wt_oa + (size_t)(wcol + t * 16 + fr) * 256 + fk;

        float4v aoa[6] = {};
        f16x8 curB[6], nxtB[6];
#pragma unroll
        for (int t = 0; t < 6; ++t)
            curB[t] = *reinterpret_cast<const f16x8*>(bb[t]);

#pragma unroll
        for (int ki = 0; ki < 8; ++ki) {
            f16x8 af = *reinterpret_cast<const f16x8*>(&sQA[fr][fk + 32 * ki]);
            if (ki < 7) {
#pragma unroll
                for (int t = 0; t < 6; ++t)
                    nxtB[t] = *reinterpret_cast<const f16x8*>(bb[t] + (ki + 1) * 32);
            }
#pragma unroll
            for (int t = 0; t < 6; ++t)
                aoa[t] = __builtin_amdgcn_mfma_f32_16x16x32_f16(af, curB[t], aoa[t], 0, 0, 0);
            if (ki < 7) {
#pragma unroll
                for (int t = 0; t < 6; ++t) curB[t] = nxtB[t];
            }
        }
        __syncthreads();   // ensure all sQA reads done before later overwrite; oa ready next
#pragma unroll
        for (int t = 0; t < 6; ++t) {
            const int col = wcol + t * 16 + dn;
            const float bv = bias_oa[col];
#pragma unroll
            for (int rr = 0; rr < 4; ++rr)
                sOA[dm0 + rr][col] = f2h(aoa[t][rr] + bv);
        }
    }
    __syncthreads();

    // ---- softmax max / inv-sum for all 16 q ----
    if (tid < 128) {
        const int q = tid >> 3, h = tid & 7;
        float m = -1e30f;
#pragma unroll
        for (int i = 0; i < 16; ++i) m = fmaxf(m, h2f(sOA[q][256 + h * 16 + i]));
        float s = 0.f;
#pragma unroll
        for (int i = 0; i < 16; ++i) s += __expf(h2f(sOA[q][256 + h * 16 + i]) - m);
        sMS[q][h][0] = m;
        sMS[q][h][1] = 1.f / s;
    }
    __syncthreads();

    // ---- two half-groups: pack then gather ----
#pragma unroll 1
    for (int half = 0; half < 2; ++half) {
        // pack 8 queries (1024 entities, 4/thread)
#pragma unroll
        for (int k = 0; k < 4; ++k) {
            const int e   = tid + k * 256;
            const int q8  = e >> 7;
            const int t   = e & 127;
            const int q   = half * 8 + q8;
            const int h   = t >> 4;
            const int lp  = t & 15;
            const int lvl = lp >> 2;
            const int p   = lp & 3;
            const int bq  = min(q0 + q, M_ - 1);

            const float wgt = __expf(h2f(sOA[q][256 + t]) - sMS[q][h][0]) * sMS[q][h][1];

            const int Wi = c_W[lvl], Hi = c_H[lvl], st = c_start[lvl];
            const float rx = refp[((size_t)bq * NL_ + lvl) * 2 + 0];
            const float ry = refp[((size_t)bq * NL_ + lvl) * 2 + 1];
            const float ox = h2f(sOA[q][h * 32 + lvl * 8 + p * 2 + 0]);
            const float oy = h2f(sOA[q][h * 32 + lvl * 8 + p * 2 + 1]);
            const float x = rx * (float)Wi + ox - 0.5f;
            const float y = ry * (float)Hi + oy - 0.5f;

            const float x0f = floorf(x), y0f = floorf(y);
            const int   x0 = (int)x0f,   y0 = (int)y0f;
            const float wx1 = x - x0f, wx0 = 1.f - wx1;
            const float wy1 = y - y0f, wy0 = 1.f - wy1;

            const int   cx[4] = {x0, x0 + 1, x0,     x0 + 1};
            const int   cy[4] = {y0, y0,     y0 + 1, y0 + 1};
            const float cw[4] = {wx0 * wy0, wx1 * wy0, wx0 * wy1, wx1 * wy1};
#pragma unroll
            for (int c = 0; c < 4; ++c) {
                const bool inb = (cx[c] >= 0) & (cx[c] < Wi) & (cy[c] >= 0) & (cy[c] < Hi);
                const int xi = min(max(cx[c], 0), Wi - 1);
                const int yi = min(max(cy[c], 0), Hi - 1);
                const int idx = st + yi * Wi + xi;
                const unsigned short wh = f2h(inb ? wgt * cw[c] : 0.f);
                sPack[q8][c][lp][h] = idx | ((int)wh << 16);
            }
        }
        __syncthreads();

        // gather 8 queries: thread = (q8, h, d4)
        {
            const int q8 = tid >> 5;
            const int q  = half * 8 + q8;
            const int h  = (tid >> 2) & 7;
            const int d4 = tid & 3;
            const int bq = q0 + q;
            const int b  = min(bq, M_ - 1) / L_;
            const unsigned short* vb = val + (size_t)b * S_ * 256 + h * 32 + d4 * 8;

            f16x2 A0{}, A1{}, A2{}, A3{};
#pragma unroll 8
            for (int i = 0; i < 64; ++i) {
                const int lp = i >> 2;
                const int c  = i & 3;
                const int pk = sPack[q8][c][lp][h];
                const unsigned wb = (unsigned)pk >> 16;
                const f16x2 w2 = __builtin_bit_cast(f16x2, (wb << 16) | wb);
                const int4 u = *reinterpret_cast<const int4*>(
                    vb + (size_t)((unsigned)pk & 0xffffu) * 256);
                A0 += w2 * __builtin_bit_cast(f16x2, u.x);
                A1 += w2 * __builtin_bit_cast(f16x2, u.y);
                A2 += w2 * __builtin_bit_cast(f16x2, u.z);
                A3 += w2 * __builtin_bit_cast(f16x2, u.w);
            }
            int4 o;
            o.x = __builtin_bit_cast(int, A0);
            o.y = __builtin_bit_cast(int, A1);
            o.z = __builtin_bit_cast(int, A2);
            o.w = __builtin_bit_cast(int, A3);
            *reinterpret_cast<int4*>(&sQA[q][h * 32 + d4 * 8]) = o;
        }
        __syncthreads();
    }

    // ---- phase D: out projection (wave w -> cols w*64, 4 n-tiles) ----
    {
        const int wcol = wave * 64;
        const unsigned short* bb[4];
#pragma unroll
        for (int t = 0; t < 4; ++t)
            bb[t] = wt_out + (size_t)(wcol + t * 16 + fr) * 256 + fk;

        float4v ao[4] = {};
        f16x8 curB[4], nxtB[4];
#pragma unroll
        for (int t = 0; t < 4; ++t)
            curB[t] = *reinterpret_cast<const f16x8*>(bb[t]);

#pragma unroll
        for (int ki = 0; ki < 8; ++ki) {
            f16x8 af = *reinterpret_cast<const f16x8*>(&sQA[fr][fk + 32 * ki]);
            if (ki < 7) {
#pragma unroll
                for (int t = 0; t < 4; ++t)
                    nxtB[t] = *reinterpret_cast<const f16x8*>(bb[t] + (ki + 1) * 32);
            }
#pragma unroll
            for (int t = 0; t < 4; ++t)
                ao[t] = __builtin_amdgcn_mfma_f32_16x16x32_f16(af, curB[t], ao[t], 0, 0, 0);
            if (ki < 7) {
#pragma unroll
                for (int t = 0; t < 4; ++t) curB[t] = nxtB[t];
            }
        }

#pragma unroll
        for (int t = 0; t < 4; ++t) {
            const int col = wcol + t * 16 + dn;
            const float bv = b_out[col];
#pragma unroll
            for (int rr = 0; rr < 4; ++rr) {
                const int bq = q0 + dm0 + rr;
                if (bq < M_)
                    out[(size_t)bq * 256 + col] = ao[t][rr] + bv;
            }
        }
    }
}

// ---------------------------------------------------------------------------
extern "C" void kernel_launch(void* const* d_in, const int* in_sizes, int n_in,
                              void* d_out, int out_size, void* d_ws, size_t ws_size,
                              hipStream_t stream) {
    const float* query  = (const float*)d_in[0];
    const float* refp   = (const float*)d_in[1];
    const float* value  = (const float*)d_in[2];
    const float* W_val  = (const float*)d_in[3];
    const float* b_val  = (const float*)d_in[4];
    const float* W_off  = (const float*)d_in[5];
    const float* b_off  = (const float*)d_in[6];
    const float* W_attn = (const float*)d_in[7];
    const float* b_attn = (const float*)d_in[8];
    const float* W_out  = (const float*)d_in[9];
    const float* b_out  = (const float*)d_in[10];
    float* out = (float*)d_out;

    char* ws = (char*)d_ws;
    const size_t mb = (size_t)M_ * 256;
    unsigned short* val_f16 = (unsigned short*)ws;  ws += mb * 2;
    unsigned short* wt_val  = (unsigned short*)ws;  ws += 65536 * 2;
    unsigned short* wt_oa   = (unsigned short*)ws;  ws += 98304 * 2;
    unsigned short* wt_out  = (unsigned short*)ws;  ws += 65536 * 2;
    float*          bias_oa = (float*)ws;           ws += 384 * 4;

    dim3 blk(256);

    prep_weights<<<dim3(898), blk, 0, stream>>>(
        W_val, W_off, W_attn, b_off, b_attn, W_out, wt_val, wt_oa, wt_out, bias_oa);

    val_proj<<<dim3((M_ + 31) / 32), blk, 0, stream>>>(value, wt_val, b_val, val_f16);

    mega<<<dim3((M_ + 15) / 16), blk, 0, stream>>>(
        val_f16, query, refp, wt_oa, wt_out, bias_oa, b_out, out);
}

// Round 9
// 226.334 us; speedup vs baseline: 1.0304x; 1.0304x over previous
//
#include <hip/hip_runtime.h>
#include <hip/hip_bf16.h>
#include <math.h>

// Problem constants
#define B_    2
#define NH_   8
#define NL_   4
#define NP_   4
#define HD_   32
#define S_    13294
#define L_    13294
#define M_    26588

__device__ __constant__ int c_H[NL_]     = {100, 50, 25, 13};
__device__ __constant__ int c_W[NL_]     = {100, 50, 25, 13};
__device__ __constant__ int c_start[NL_] = {0, 10000, 12500, 13125};

typedef __attribute__((ext_vector_type(8))) _Float16 f16x8;
typedef __attribute__((ext_vector_type(4))) _Float16 f16x4;
typedef __attribute__((ext_vector_type(2))) _Float16 f16x2;
typedef __attribute__((ext_vector_type(4))) float    float4v;

__device__ __forceinline__ unsigned short f2h(float f) {
    _Float16 h = (_Float16)f;
    return __builtin_bit_cast(unsigned short, h);
}
__device__ __forceinline__ float h2f(unsigned short u) {
    _Float16 h = __builtin_bit_cast(_Float16, u);
    return (float)h;
}
__device__ __forceinline__ f16x2 pkrtz(float a, float b) {
    return __builtin_bit_cast(f16x2, __builtin_amdgcn_cvt_pkrtz(a, b));
}

// ---------------------------------------------------------------------------
// Weight prep: transpose W's to [N][K] fp16, fused off|attn weights + bias.
// ---------------------------------------------------------------------------
__global__ __launch_bounds__(256) void prep_weights(
    const float* __restrict__ W_val, const float* __restrict__ W_off,
    const float* __restrict__ W_attn, const float* __restrict__ b_off,
    const float* __restrict__ b_attn, const float* __restrict__ W_out,
    unsigned short* __restrict__ wt_val, unsigned short* __restrict__ wt_oa,
    unsigned short* __restrict__ wt_out, float* __restrict__ bias_oa)
{
    int i = blockIdx.x * 256 + threadIdx.x;
    if (i < 65536) {
        int n = i >> 8, k = i & 255;
        wt_val[i] = f2h(W_val[k * 256 + n]);
    } else if (i < 65536 + 98304) {
        int j = i - 65536;
        int n = j >> 8, k = j & 255;   // n in [0,384)
        float v = (n < 256) ? W_off[k * 256 + n] : W_attn[k * 128 + (n - 256)];
        wt_oa[j] = f2h(v);
    } else if (i < 65536 + 98304 + 65536) {
        int j = i - 163840;
        int n = j >> 8, k = j & 255;
        wt_out[j] = f2h(W_out[k * 256 + n]);
    } else if (i < 229376 + 384) {
        int j = i - 229376;
        bias_oa[j] = (j < 256) ? b_off[j] : b_attn[j - 256];
    }
}

// ---------------------------------------------------------------------------
// 32-row x N-col MFMA GEMM body (round-8 val_proj structure, generalized).
//   4 waves; wave w = 32 rows x N/4 cols (2 x NT 16x16 tiles, NT = N/64... per
//   wave: N/4 cols / 16 = N/64? N=256 -> 4 tiles, N=384 -> 6 tiles).
//   A: depth-4 register ring (~3 K-iters vmcnt slack vs HBM latency) ->
//      double-buffered LDS, ONE barrier per K-iter.
//   B: direct-from-global per-lane 16B fragments, depth-2 ring (L2-resident).
//   OUT: 0 = fp16 stride 256, 1 = fp16 stride 384, 2 = fp32 stride 256.
// ---------------------------------------------------------------------------
template<int N, int OUT, bool AF32>
__device__ __forceinline__ void gemm32_body(
    const void* __restrict__ Av,
    const unsigned short* __restrict__ WT,
    const float* __restrict__ bias,
    void* __restrict__ Cv,
    unsigned short (* __restrict__ As)[32][40])
{
    constexpr int NT = N / 64;      // B tiles per wave

    const int tid  = threadIdx.x;
    const int lane = tid & 63;
    const int wave = tid >> 6;
    const int rowBase = blockIdx.x * 32;
    const int wcol = wave * (N / 4);

    const int r  = tid >> 3;           // 0..31 A row
    const int ko = (tid & 7) * 4;      // element offset within BK=32
    int arow = rowBase + r; if (arow >= M_) arow = M_ - 1;   // clamp; stores guarded

    const int fr = lane & 15;
    const int fk = (lane >> 4) * 8;

    const unsigned short* bb[NT];
#pragma unroll
    for (int t = 0; t < NT; ++t)
        bb[t] = WT + (size_t)(wcol + t * 16 + fr) * 256 + fk;

    float4 raf[4];
    f16x4  rah[4];
    f16x8 curB[NT], nxtB[NT];
    float4v acc[2][NT] = {};

    auto ldA = [&](int slot, int bk) {
        if constexpr (AF32) {
            raf[slot] = *reinterpret_cast<const float4*>(
                (const float*)Av + (size_t)arow * 256 + bk * 32 + ko);
        } else {
            rah[slot] = *reinterpret_cast<const f16x4*>(
                (const unsigned short*)Av + (size_t)arow * 256 + bk * 32 + ko);
        }
    };
    auto stA = [&](int slot, int buf) {
        f16x4 v;
        if constexpr (AF32) {
            f16x2 p0 = pkrtz(raf[slot].x, raf[slot].y);
            f16x2 p1 = pkrtz(raf[slot].z, raf[slot].w);
            v[0] = p0[0]; v[1] = p0[1]; v[2] = p1[0]; v[3] = p1[1];
        } else {
            v = rah[slot];
        }
        *reinterpret_cast<f16x4*>(&As[buf][r][ko]) = v;
    };

    // prologue: 4 A-chunks + first B in flight
#pragma unroll
    for (int c = 0; c < 4; ++c) ldA(c, c);
#pragma unroll
    for (int t = 0; t < NT; ++t)
        curB[t] = *reinterpret_cast<const f16x8*>(bb[t]);
    stA(0, 0);

#pragma unroll
    for (int it = 0; it < 8; ++it) {
        __syncthreads();
        f16x8 af0 = *reinterpret_cast<const f16x8*>(&As[it & 1][fr][fk]);
        f16x8 af1 = *reinterpret_cast<const f16x8*>(&As[it & 1][16 + fr][fk]);
        if (it < 7) {
            stA((it + 1) & 3, (it + 1) & 1);
            if (it < 4) ldA(it & 3, it + 4);     // refill ring ~3 iters ahead
#pragma unroll
            for (int t = 0; t < NT; ++t)
                nxtB[t] = *reinterpret_cast<const f16x8*>(bb[t] + (it + 1) * 32);
        }
#pragma unroll
        for (int nt = 0; nt < NT; ++nt) {
            acc[0][nt] = __builtin_amdgcn_mfma_f32_16x16x32_f16(af0, curB[nt], acc[0][nt], 0, 0, 0);
            acc[1][nt] = __builtin_amdgcn_mfma_f32_16x16x32_f16(af1, curB[nt], acc[1][nt], 0, 0, 0);
        }
        if (it < 7) {
#pragma unroll
            for (int t = 0; t < NT; ++t) curB[t] = nxtB[t];
        }
    }

    const int dn  = lane & 15;
    const int dm0 = (lane >> 4) * 4;
#pragma unroll
    for (int mt = 0; mt < 2; ++mt)
#pragma unroll
        for (int nt = 0; nt < NT; ++nt) {
            const int col = wcol + nt * 16 + dn;
            const float bv = bias[col];
#pragma unroll
            for (int rr = 0; rr < 4; ++rr) {
                const int row = rowBase + mt * 16 + dm0 + rr;
                if (row < M_) {
                    const float v = acc[mt][nt][rr] + bv;
                    if constexpr (OUT == 0)
                        ((unsigned short*)Cv)[(size_t)row * 256 + col] = f2h(v);
                    else if constexpr (OUT == 1)
                        ((unsigned short*)Cv)[(size_t)row * 384 + col] = f2h(v);
                    else
                        ((float*)Cv)[(size_t)row * 256 + col] = v;
                }
            }
        }
}

// value proj (y=0, fp16 out) + query off/attn proj (y=1, fp16 out), merged.
__global__ __launch_bounds__(256) void gemm_vq(
    const float* __restrict__ value, const float* __restrict__ query,
    const unsigned short* __restrict__ wt_val, const unsigned short* __restrict__ wt_oa,
    const float* __restrict__ b_val, const float* __restrict__ bias_oa,
    unsigned short* __restrict__ val_f16, unsigned short* __restrict__ oa_f16)
{
    __shared__ unsigned short As[2][32][40];
    if (blockIdx.y == 0)
        gemm32_body<256, 0, true>(value, wt_val, b_val, val_f16, As);
    else
        gemm32_body<384, 1, true>(query, wt_oa, bias_oa, oa_f16, As);
}

// output projection: out = acc_f16 @ wt_out^T + b_out (fp32 out)
__global__ __launch_bounds__(256) void gemm_out4(
    const unsigned short* __restrict__ Af16,
    const unsigned short* __restrict__ WT,
    const float* __restrict__ bias, float* __restrict__ C)
{
    __shared__ unsigned short As[2][32][40];
    gemm32_body<256, 2, false>(Af16, WT, bias, C, As);
}

// ---------------------------------------------------------------------------
// Deformable sampling v5 (unchanged from round 7: ~52 us, L2-gather-bound).
// ---------------------------------------------------------------------------
__global__ __launch_bounds__(256) void deform_sample_v5(
    const unsigned short* __restrict__ val,  // [B,S,256] fp16
    const float* __restrict__ refp,          // [B,L,4,2]
    const unsigned short* __restrict__ oa,   // [M,384] fp16
    unsigned short* __restrict__ acc)        // [M,256] fp16
{
    const int tid = threadIdx.x;
    const int q0  = blockIdx.x * 8;

    __shared__ unsigned short sLog[8][128];
    __shared__ float sMS[8][8][2];
    __shared__ int   sPack[8][4][16][8];

    {
        const int q  = tid >> 5;
        const int f  = tid & 31;
        const int bq = min(q0 + q, M_ - 1);
        *reinterpret_cast<int2*>(&sLog[q][f * 4]) =
            *reinterpret_cast<const int2*>(oa + (size_t)bq * 384 + 256 + f * 4);
    }
    __syncthreads();

    if (tid < 64) {
        const int q = tid >> 3, h = tid & 7;
        float m = -1e30f;
#pragma unroll
        for (int i = 0; i < 16; ++i) m = fmaxf(m, h2f(sLog[q][h * 16 + i]));
        float s = 0.f;
#pragma unroll
        for (int i = 0; i < 16; ++i) s += __expf(h2f(sLog[q][h * 16 + i]) - m);
        sMS[q][h][0] = m;
        sMS[q][h][1] = 1.f / s;
    }
    __syncthreads();

#pragma unroll
    for (int k = 0; k < 4; ++k) {
        const int e   = tid + k * 256;
        const int q   = e >> 7;
        const int t   = e & 127;
        const int h   = t >> 4;
        const int lp  = t & 15;
        const int lvl = lp >> 2;
        const int p   = lp & 3;
        const int bq  = min(q0 + q, M_ - 1);

        const float wgt = __expf(h2f(sLog[q][t]) - sMS[q][h][0]) * sMS[q][h][1];

        const int Wi = c_W[lvl], Hi = c_H[lvl], st = c_start[lvl];
        const float rx = refp[((size_t)bq * NL_ + lvl) * 2 + 0];
        const float ry = refp[((size_t)bq * NL_ + lvl) * 2 + 1];
        const float ox = h2f(oa[(size_t)bq * 384 + h * 32 + lvl * 8 + p * 2 + 0]);
        const float oy = h2f(oa[(size_t)bq * 384 + h * 32 + lvl * 8 + p * 2 + 1]);
        const float x = rx * (float)Wi + ox - 0.5f;
        const float y = ry * (float)Hi + oy - 0.5f;

        const float x0f = floorf(x), y0f = floorf(y);
        const int   x0 = (int)x0f,   y0 = (int)y0f;
        const float wx1 = x - x0f, wx0 = 1.f - wx1;
        const float wy1 = y - y0f, wy0 = 1.f - wy1;

        const int   cx[4] = {x0, x0 + 1, x0,     x0 + 1};
        const int   cy[4] = {y0, y0,     y0 + 1, y0 + 1};
        const float cw[4] = {wx0 * wy0, wx1 * wy0, wx0 * wy1, wx1 * wy1};
#pragma unroll
        for (int c = 0; c < 4; ++c) {
            const bool inb = (cx[c] >= 0) & (cx[c] < Wi) & (cy[c] >= 0) & (cy[c] < Hi);
            const int xi = min(max(cx[c], 0), Wi - 1);
            const int yi = min(max(cy[c], 0), Hi - 1);
            const int idx = st + yi * Wi + xi;          // < 13294: fits 16 bits
            const unsigned short wh = f2h(inb ? wgt * cw[c] : 0.f);
            sPack[q][c][lp][h] = idx | ((int)wh << 16);
        }
    }
    __syncthreads();

    const int q  = tid >> 5;
    const int h  = (tid >> 2) & 7;
    const int d4 = tid & 3;
    const int bq = q0 + q;
    const int b  = min(bq, M_ - 1) / L_;
    const unsigned short* vb = val + (size_t)b * S_ * 256 + h * 32 + d4 * 8;

    f16x2 A0{}, A1{}, A2{}, A3{};
#pragma unroll 8
    for (int i = 0; i < 64; ++i) {
        const int lp = i >> 2;
        const int c  = i & 3;
        const int pk = sPack[q][c][lp][h];
        const unsigned wb = (unsigned)pk >> 16;
        const f16x2 w2 = __builtin_bit_cast(f16x2, (wb << 16) | wb);
        const int4 u = *reinterpret_cast<const int4*>(
            vb + (size_t)((unsigned)pk & 0xffffu) * 256);
        A0 += w2 * __builtin_bit_cast(f16x2, u.x);
        A1 += w2 * __builtin_bit_cast(f16x2, u.y);
        A2 += w2 * __builtin_bit_cast(f16x2, u.z);
        A3 += w2 * __builtin_bit_cast(f16x2, u.w);
    }
    if (bq < M_) {
        int4 o;
        o.x = __builtin_bit_cast(int, A0);
        o.y = __builtin_bit_cast(int, A1);
        o.z = __builtin_bit_cast(int, A2);
        o.w = __builtin_bit_cast(int, A3);
        *reinterpret_cast<int4*>(acc + (size_t)bq * 256 + h * 32 + d4 * 8) = o;
    }
}

// ---------------------------------------------------------------------------
extern "C" void kernel_launch(void* const* d_in, const int* in_sizes, int n_in,
                              void* d_out, int out_size, void* d_ws, size_t ws_size,
                              hipStream_t stream) {
    const float* query  = (const float*)d_in[0];
    const float* refp   = (const float*)d_in[1];
    const float* value  = (const float*)d_in[2];
    const float* W_val  = (const float*)d_in[3];
    const float* b_val  = (const float*)d_in[4];
    const float* W_off  = (const float*)d_in[5];
    const float* b_off  = (const float*)d_in[6];
    const float* W_attn = (const float*)d_in[7];
    const float* b_attn = (const float*)d_in[8];
    const float* W_out  = (const float*)d_in[9];
    const float* b_out  = (const float*)d_in[10];
    float* out = (float*)d_out;

    char* ws = (char*)d_ws;
    const size_t mb = (size_t)M_ * 256;
    unsigned short* val_f16 = (unsigned short*)ws;  ws += mb * 2;
    unsigned short* acc_f16 = (unsigned short*)ws;  ws += mb * 2;
    unsigned short* oa_f16  = (unsigned short*)ws;  ws += (size_t)M_ * 384 * 2;
    unsigned short* wt_val  = (unsigned short*)ws;  ws += 65536 * 2;
    unsigned short* wt_oa   = (unsigned short*)ws;  ws += 98304 * 2;
    unsigned short* wt_out  = (unsigned short*)ws;  ws += 65536 * 2;
    float*          bias_oa = (float*)ws;           ws += 384 * 4;

    dim3 blk(256);

    prep_weights<<<dim3(898), blk, 0, stream>>>(
        W_val, W_off, W_attn, b_off, b_attn, W_out, wt_val, wt_oa, wt_out, bias_oa);

    // value proj + off/attn proj: 32-row tiles, deep prefetch, 1662 blocks
    gemm_vq<<<dim3((M_ + 31) / 32, 2), blk, 0, stream>>>(
        value, query, wt_val, wt_oa, b_val, bias_oa, val_f16, oa_f16);

    // softmax + sampling
    deform_sample_v5<<<dim3((M_ + 7) / 8), blk, 0, stream>>>(val_f16, refp, oa_f16, acc_f16);

    // output projection: 32-row tiles, 831 blocks
    gemm_out4<<<dim3((M_ + 31) / 32), blk, 0, stream>>>(acc_f16, wt_out, b_out, out);
}

// Round 11
// 215.803 us; speedup vs baseline: 1.0807x; 1.0488x over previous
//
#include <hip/hip_runtime.h>
#include <hip/hip_bf16.h>
#include <math.h>

// Problem constants
#define B_    2
#define NH_   8
#define NL_   4
#define NP_   4
#define HD_   32
#define S_    13294
#define L_    13294
#define M_    26588
#define NTILE 831      // ceil(M/32)

__device__ __constant__ int c_H[NL_]     = {100, 50, 25, 13};
__device__ __constant__ int c_W[NL_]     = {100, 50, 25, 13};
__device__ __constant__ int c_start[NL_] = {0, 10000, 12500, 13125};

typedef __attribute__((ext_vector_type(8))) _Float16 f16x8;
typedef __attribute__((ext_vector_type(4))) _Float16 f16x4;
typedef __attribute__((ext_vector_type(2))) _Float16 f16x2;
typedef __attribute__((ext_vector_type(4))) float    float4v;

__device__ __forceinline__ unsigned short f2h(float f) {
    _Float16 h = (_Float16)f;
    return __builtin_bit_cast(unsigned short, h);
}
__device__ __forceinline__ float h2f(unsigned short u) {
    _Float16 h = __builtin_bit_cast(_Float16, u);
    return (float)h;
}
__device__ __forceinline__ f16x2 pkrtz(float a, float b) {
    return __builtin_bit_cast(f16x2, __builtin_amdgcn_cvt_pkrtz(a, b));
}

// ---------------------------------------------------------------------------
// Weight prep: transpose W's to [N][K] fp16, fused off|attn weights + bias.
// ---------------------------------------------------------------------------
__global__ __launch_bounds__(256) void prep_weights(
    const float* __restrict__ W_val, const float* __restrict__ W_off,
    const float* __restrict__ W_attn, const float* __restrict__ b_off,
    const float* __restrict__ b_attn, const float* __restrict__ W_out,
    unsigned short* __restrict__ wt_val, unsigned short* __restrict__ wt_oa,
    unsigned short* __restrict__ wt_out, float* __restrict__ bias_oa)
{
    int i = blockIdx.x * 256 + threadIdx.x;
    if (i < 65536) {
        int n = i >> 8, k = i & 255;
        wt_val[i] = f2h(W_val[k * 256 + n]);
    } else if (i < 65536 + 98304) {
        int j = i - 65536;
        int n = j >> 8, k = j & 255;   // n in [0,384)
        float v = (n < 256) ? W_off[k * 256 + n] : W_attn[k * 128 + (n - 256)];
        wt_oa[j] = f2h(v);
    } else if (i < 65536 + 98304 + 65536) {
        int j = i - 163840;
        int n = j >> 8, k = j & 255;
        wt_out[j] = f2h(W_out[k * 256 + n]);
    } else if (i < 229376 + 384) {
        int j = i - 229376;
        bias_oa[j] = (j < 256) ? b_off[j] : b_attn[j - 256];
    }
}

// ---------------------------------------------------------------------------
// Persistent-block GEMM body: wave's B slice fully register-resident
// (NT x 8 f16x8 = NT*32 VGPRs, loaded ONCE), then loop over 32-row tiles
// [t0,t1) with depth-4 A-register ring -> double-buffered LDS, one barrier
// per K-iter. Steady state has ZERO B loads: only A-stream + MFMA.
// Ring discipline (verified r8/r9): at iteration g, stA consumes slot
// (g+1)&3 (chunk g+1); ldA refills slot g&3 (freed last iter) with chunk
// g+4 -> ~3 iterations of vmcnt slack.
//   OUT: 0 = fp16 stride 256, 1 = fp16 stride 384, 2 = fp32 stride 256.
// ---------------------------------------------------------------------------
template<int NT, int OUT, bool AF32>
__device__ __forceinline__ void gemm_persist(
    const void* __restrict__ Av,
    const unsigned short* __restrict__ WT,
    const float* __restrict__ bias,
    void* __restrict__ Cv,
    int t0, int t1, int colBase,
    unsigned short (* __restrict__ As)[32][40])
{
    const int tid  = threadIdx.x;
    const int lane = tid & 63;
    const int wave = tid >> 6;
    const int wcol = colBase + wave * (NT * 16);

    const int r  = tid >> 3;           // 0..31: A row within tile
    const int ko = (tid & 7) * 4;      // element offset within BK=32
    const int fr = lane & 15;
    const int fk = (lane >> 4) * 8;

    // ---- B: load wave's full col-slice into registers (once) ----
    f16x8 Bf[NT][8];
#pragma unroll
    for (int t = 0; t < NT; ++t) {
        const unsigned short* bp = WT + (size_t)(wcol + t * 16 + fr) * 256 + fk;
#pragma unroll
        for (int kc = 0; kc < 8; ++kc)
            Bf[t][kc] = *reinterpret_cast<const f16x8*>(bp + kc * 32);
    }

    // ---- A chunk ring (depth 4); chunk g = (tile-t0)*8 + bk ----
    const int nChunk = (t1 - t0) * 8;
    float4 raf[4];
    f16x4  rah[4];

    auto ldA = [&](int slot, int g) {
        if (g >= nChunk) g = nChunk - 1;
        const int tile = t0 + (g >> 3);
        int row = tile * 32 + r;
        if (row >= M_) row = M_ - 1;               // clamp; stores guarded
        const int kk = (g & 7) * 32 + ko;
        if constexpr (AF32)
            raf[slot] = *reinterpret_cast<const float4*>(
                (const float*)Av + (size_t)row * 256 + kk);
        else
            rah[slot] = *reinterpret_cast<const f16x4*>(
                (const unsigned short*)Av + (size_t)row * 256 + kk);
    };
    auto stA = [&](int slot, int buf) {
        f16x4 v;
        if constexpr (AF32) {
            f16x2 p0 = pkrtz(raf[slot].x, raf[slot].y);
            f16x2 p1 = pkrtz(raf[slot].z, raf[slot].w);
            v[0] = p0[0]; v[1] = p0[1]; v[2] = p1[0]; v[3] = p1[1];
        } else {
            v = rah[slot];
        }
        *reinterpret_cast<f16x4*>(&As[buf][r][ko]) = v;
    };

#pragma unroll
    for (int c = 0; c < 4; ++c) ldA(c, c);
    stA(0, 0);

    const int dn  = lane & 15;
    const int dm0 = (lane >> 4) * 4;

    int g = 0;
    for (int tile = t0; tile < t1; ++tile) {
        float4v acc[2][NT] = {};
#pragma unroll
        for (int it = 0; it < 8; ++it) {
            __syncthreads();
            f16x8 af0 = *reinterpret_cast<const f16x8*>(&As[it & 1][fr][fk]);
            f16x8 af1 = *reinterpret_cast<const f16x8*>(&As[it & 1][16 + fr][fk]);
            if (g + 1 < nChunk) {
                stA((g + 1) & 3, (g + 1) & 1);     // stage chunk g+1 (next iter's buf)
                ldA(g & 3, g + 4);                 // refill slot freed last iter
            }
#pragma unroll
            for (int nt = 0; nt < NT; ++nt) {
                acc[0][nt] = __builtin_amdgcn_mfma_f32_16x16x32_f16(af0, Bf[nt][it], acc[0][nt], 0, 0, 0);
                acc[1][nt] = __builtin_amdgcn_mfma_f32_16x16x32_f16(af1, Bf[nt][it], acc[1][nt], 0, 0, 0);
            }
            ++g;
        }
        // tile epilogue
#pragma unroll
        for (int mt = 0; mt < 2; ++mt)
#pragma unroll
            for (int nt = 0; nt < NT; ++nt) {
                const int col = wcol + nt * 16 + dn;
                const float bv = bias[col];
#pragma unroll
                for (int rr = 0; rr < 4; ++rr) {
                    const int row = tile * 32 + mt * 16 + dm0 + rr;
                    if (row < M_) {
                        const float v = acc[mt][nt][rr] + bv;
                        if constexpr (OUT == 0)
                            ((unsigned short*)Cv)[(size_t)row * 256 + col] = f2h(v);
                        else if constexpr (OUT == 1)
                            ((unsigned short*)Cv)[(size_t)row * 384 + col] = f2h(v);
                        else
                            ((float*)Cv)[(size_t)row * 256 + col] = v;
                    }
                }
            }
    }
}

// value proj + off/attn proj, persistent blocks.
//   bid 0..207   : val   (NT=4, cols 0..255),   4 tiles each
//   bid 208..415 : oa G0 (NT=4, cols 0..255),   4 tiles each
//   bid 416..519 : oa G1 (NT=2, cols 256..383), 8 tiles each
__global__ __launch_bounds__(256, 2) void gemm_vq_p(
    const float* __restrict__ value, const float* __restrict__ query,
    const unsigned short* __restrict__ wt_val, const unsigned short* __restrict__ wt_oa,
    const float* __restrict__ b_val, const float* __restrict__ bias_oa,
    unsigned short* __restrict__ val_f16, unsigned short* __restrict__ oa_f16)
{
    __shared__ unsigned short As[2][32][40];
    const int bid = blockIdx.x;
    if (bid < 208) {
        const int t0 = bid * 4, t1 = min(t0 + 4, NTILE);
        gemm_persist<4, 0, true>(value, wt_val, b_val, val_f16, t0, t1, 0, As);
    } else if (bid < 416) {
        const int t0 = (bid - 208) * 4, t1 = min(t0 + 4, NTILE);
        gemm_persist<4, 1, true>(query, wt_oa, bias_oa, oa_f16, t0, t1, 0, As);
    } else {
        const int t0 = (bid - 416) * 8, t1 = min(t0 + 8, NTILE);
        gemm_persist<2, 1, true>(query, wt_oa, bias_oa, oa_f16, t0, t1, 256, As);
    }
}

// output projection, persistent blocks: 416 blocks x 2 tiles.
__global__ __launch_bounds__(256, 2) void gemm_out_p(
    const unsigned short* __restrict__ Af16,
    const unsigned short* __restrict__ WT,
    const float* __restrict__ bias, float* __restrict__ C)
{
    __shared__ unsigned short As[2][32][40];
    const int t0 = blockIdx.x * 2, t1 = min(t0 + 2, NTILE);
    gemm_persist<4, 2, false>(Af16, WT, bias, C, t0, t1, 0, As);
}

// ---------------------------------------------------------------------------
// Deformable sampling v5 (unchanged: ~52 us, L2-gather-bound).
// ---------------------------------------------------------------------------
__global__ __launch_bounds__(256) void deform_sample_v5(
    const unsigned short* __restrict__ val,  // [B,S,256] fp16
    const float* __restrict__ refp,          // [B,L,4,2]
    const unsigned short* __restrict__ oa,   // [M,384] fp16
    unsigned short* __restrict__ acc)        // [M,256] fp16
{
    const int tid = threadIdx.x;
    const int q0  = blockIdx.x * 8;

    __shared__ unsigned short sLog[8][128];
    __shared__ float sMS[8][8][2];
    __shared__ int   sPack[8][4][16][8];

    {
        const int q  = tid >> 5;
        const int f  = tid & 31;
        const int bq = min(q0 + q, M_ - 1);
        *reinterpret_cast<int2*>(&sLog[q][f * 4]) =
            *reinterpret_cast<const int2*>(oa + (size_t)bq * 384 + 256 + f * 4);
    }
    __syncthreads();

    if (tid < 64) {
        const int q = tid >> 3, h = tid & 7;
        float m = -1e30f;
#pragma unroll
        for (int i = 0; i < 16; ++i) m = fmaxf(m, h2f(sLog[q][h * 16 + i]));
        float s = 0.f;
#pragma unroll
        for (int i = 0; i < 16; ++i) s += __expf(h2f(sLog[q][h * 16 + i]) - m);
        sMS[q][h][0] = m;
        sMS[q][h][1] = 1.f / s;
    }
    __syncthreads();

#pragma unroll
    for (int k = 0; k < 4; ++k) {
        const int e   = tid + k * 256;
        const int q   = e >> 7;
        const int t   = e & 127;
        const int h   = t >> 4;
        const int lp  = t & 15;
        const int lvl = lp >> 2;
        const int p   = lp & 3;
        const int bq  = min(q0 + q, M_ - 1);

        const float wgt = __expf(h2f(sLog[q][t]) - sMS[q][h][0]) * sMS[q][h][1];

        const int Wi = c_W[lvl], Hi = c_H[lvl], st = c_start[lvl];
        const float rx = refp[((size_t)bq * NL_ + lvl) * 2 + 0];
        const float ry = refp[((size_t)bq * NL_ + lvl) * 2 + 1];
        const float ox = h2f(oa[(size_t)bq * 384 + h * 32 + lvl * 8 + p * 2 + 0]);
        const float oy = h2f(oa[(size_t)bq * 384 + h * 32 + lvl * 8 + p * 2 + 1]);
        const float x = rx * (float)Wi + ox - 0.5f;
        const float y = ry * (float)Hi + oy - 0.5f;

        const float x0f = floorf(x), y0f = floorf(y);
        const int   x0 = (int)x0f,   y0 = (int)y0f;
        const float wx1 = x - x0f, wx0 = 1.f - wx1;
        const float wy1 = y - y0f, wy0 = 1.f - wy1;

        const int   cx[4] = {x0, x0 + 1, x0,     x0 + 1};
        const int   cy[4] = {y0, y0,     y0 + 1, y0 + 1};
        const float cw[4] = {wx0 * wy0, wx1 * wy0, wx0 * wy1, wx1 * wy1};
#pragma unroll
        for (int c = 0; c < 4; ++c) {
            const bool inb = (cx[c] >= 0) & (cx[c] < Wi) & (cy[c] >= 0) & (cy[c] < Hi);
            const int xi = min(max(cx[c], 0), Wi - 1);
            const int yi = min(max(cy[c], 0), Hi - 1);
            const int idx = st + yi * Wi + xi;          // < 13294: fits 16 bits
            const unsigned short wh = f2h(inb ? wgt * cw[c] : 0.f);
            sPack[q][c][lp][h] = idx | ((int)wh << 16);
        }
    }
    __syncthreads();

    const int q  = tid >> 5;
    const int h  = (tid >> 2) & 7;
    const int d4 = tid & 3;
    const int bq = q0 + q;
    const int b  = min(bq, M_ - 1) / L_;
    const unsigned short* vb = val + (size_t)b * S_ * 256 + h * 32 + d4 * 8;

    f16x2 A0{}, A1{}, A2{}, A3{};
#pragma unroll 8
    for (int i = 0; i < 64; ++i) {
        const int lp = i >> 2;
        const int c  = i & 3;
        const int pk = sPack[q][c][lp][h];
        const unsigned wb = (unsigned)pk >> 16;
        const f16x2 w2 = __builtin_bit_cast(f16x2, (wb << 16) | wb);
        const int4 u = *reinterpret_cast<const int4*>(
            vb + (size_t)((unsigned)pk & 0xffffu) * 256);
        A0 += w2 * __builtin_bit_cast(f16x2, u.x);
        A1 += w2 * __builtin_bit_cast(f16x2, u.y);
        A2 += w2 * __builtin_bit_cast(f16x2, u.z);
        A3 += w2 * __builtin_bit_cast(f16x2, u.w);
    }
    if (bq < M_) {
        int4 o;
        o.x = __builtin_bit_cast(int, A0);
        o.y = __builtin_bit_cast(int, A1);
        o.z = __builtin_bit_cast(int, A2);
        o.w = __builtin_bit_cast(int, A3);
        *reinterpret_cast<int4*>(acc + (size_t)bq * 256 + h * 32 + d4 * 8) = o;
    }
}

// ---------------------------------------------------------------------------
extern "C" void kernel_launch(void* const* d_in, const int* in_sizes, int n_in,
                              void* d_out, int out_size, void* d_ws, size_t ws_size,
                              hipStream_t stream) {
    const float* query  = (const float*)d_in[0];
    const float* refp   = (const float*)d_in[1];
    const float* value  = (const float*)d_in[2];
    const float* W_val  = (const float*)d_in[3];
    const float* b_val  = (const float*)d_in[4];
    const float* W_off  = (const float*)d_in[5];
    const float* b_off  = (const float*)d_in[6];
    const float* W_attn = (const float*)d_in[7];
    const float* b_attn = (const float*)d_in[8];
    const float* W_out  = (const float*)d_in[9];
    const float* b_out  = (const float*)d_in[10];
    float* out = (float*)d_out;

    char* ws = (char*)d_ws;
    const size_t mb = (size_t)M_ * 256;
    unsigned short* val_f16 = (unsigned short*)ws;  ws += mb * 2;
    unsigned short* acc_f16 = (unsigned short*)ws;  ws += mb * 2;
    unsigned short* oa_f16  = (unsigned short*)ws;  ws += (size_t)M_ * 384 * 2;
    unsigned short* wt_val  = (unsigned short*)ws;  ws += 65536 * 2;
    unsigned short* wt_oa   = (unsigned short*)ws;  ws += 98304 * 2;
    unsigned short* wt_out  = (unsigned short*)ws;  ws += 65536 * 2;
    float*          bias_oa = (float*)ws;           ws += 384 * 4;

    dim3 blk(256);

    prep_weights<<<dim3(898), blk, 0, stream>>>(
        W_val, W_off, W_attn, b_off, b_attn, W_out, wt_val, wt_oa, wt_out, bias_oa);

    // value proj + off/attn proj: persistent blocks, B register-resident
    gemm_vq_p<<<dim3(520), blk, 0, stream>>>(
        value, query, wt_val, wt_oa, b_val, bias_oa, val_f16, oa_f16);

    // softmax + sampling
    deform_sample_v5<<<dim3((M_ + 7) / 8), blk, 0, stream>>>(val_f16, refp, oa_f16, acc_f16);

    // output projection: persistent blocks
    gemm_out_p<<<dim3(416), blk, 0, stream>>>(acc_f16, wt_out, b_out, out);
}